// Round 11
// baseline (1079.682 us; speedup 1.0000x reference)
//
#include <hip/hip_runtime.h>
#include <hip/hip_bf16.h>
#include <math.h>

#define D_ 256
#define B_ 65536
#define C_ 1000

typedef _Float16 f16x8 __attribute__((ext_vector_type(8)));
typedef float f32x4 __attribute__((ext_vector_type(4)));

// ---------------- kernel 1: cov = bc @ bc^T in fp64, LDS-tiled; zeroes acc+counter ----
__global__ __launch_bounds__(256) void cov_kernel(const float* __restrict__ bc,
                                                  double* __restrict__ C64,
                                                  double* __restrict__ acc,
                                                  unsigned int* __restrict__ counter) {
  __shared__ float Ash[32][260];
  __shared__ float Bsh2[32][260];
  const int b = blockIdx.x, bi = b >> 3, bj = b & 7;
  const int e = threadIdx.x;
  if (b == 0 && e == 0) { *acc = 0.0; *counter = 0u; }
#pragma unroll
  for (int s = 0; s < 32; ++s) {
    int lin = s * 256 + e;
    int rr = lin >> 8, cc = lin & 255;
    Ash[rr][cc] = bc[(bi * 32 + rr) * 256 + cc];
    Bsh2[rr][cc] = bc[(bj * 32 + rr) * 256 + cc];
  }
  __syncthreads();
  const int tx = e & 15, ty = e >> 4;
  double a00 = 0, a01 = 0, a10 = 0, a11 = 0;
#pragma unroll 8
  for (int k = 0; k < 256; ++k) {
    double ar0 = (double)Ash[ty][k], ar1 = (double)Ash[ty + 16][k];
    double br0 = (double)Bsh2[tx][k], br1 = (double)Bsh2[tx + 16][k];
    a00 += ar0 * br0; a01 += ar0 * br1;
    a10 += ar1 * br0; a11 += ar1 * br1;
  }
  const int r0 = bi * 32, c0 = bj * 32;
  C64[(size_t)(r0 + ty) * D_ + c0 + tx] = a00;
  C64[(size_t)(r0 + ty) * D_ + c0 + tx + 16] = a01;
  C64[(size_t)(r0 + ty + 16) * D_ + c0 + tx] = a10;
  C64[(size_t)(r0 + ty + 16) * D_ + c0 + tx + 16] = a11;
}

// ---------------- kernel 2a: panel factor v3 — wave0 shfl-only diag + parallel subst --
// Wave 0 (64 lanes = 64 panel rows, rows in registers): per column, pivot & scaled
// column move via __shfl (v_readlane, no LDS, no barriers). Publishes Lp + rs to LDS.
// One __syncthreads. Then threads 64..255 forward-substitute one off-panel row each
// (independent; Lp reads are wave-uniform broadcasts). Arithmetic identical to the
// old per-column rank-1 path (same products, same rounding order per row).
__global__ __launch_bounds__(256, 1) void chol_panel(double* __restrict__ A, int p) {
  const int j0 = p * 64;
  const int tid = threadIdx.x;
  __shared__ double Lp[64][65];
  __shared__ double rsv[64];

  // off-panel substitution rows: tid 64..255 -> global row j0+tid (if < 256).
  const int rsub = j0 + tid;
  const bool dosub = (tid >= 64) && (rsub < D_);
  double x[64];
  if (dosub) {
#pragma unroll
    for (int k = 0; k < 64; ++k) x[k] = A[(size_t)rsub * D_ + j0 + k];  // prefetch, hides under factor
  }

  if (tid < 64) {                       // wave 0: factor 64x64 diag block
    const int r = j0 + tid;
    double pr[64];
#pragma unroll
    for (int k = 0; k < 64; ++k) pr[k] = A[(size_t)r * D_ + j0 + k];
#pragma unroll
    for (int j = 0; j < 64; ++j) {
      const double d2 = __shfl(pr[j], j, 64);
      double rs = (double)rsqrtf((float)d2);
      rs = rs * (1.5 - 0.5 * d2 * rs * rs);
      rs = rs * (1.5 - 0.5 * d2 * rs * rs);
      const double lr = pr[j] * rs;     // lane j: sqrt(d2); lanes>j: L_rj; lanes<j: junk (unused)
      pr[j] = lr;
      if (tid == j) rsv[j] = rs;
#pragma unroll
      for (int k = j + 1; k < 64; ++k) {
        const double lkj = __shfl(lr, k, 64);   // L[j0+k][col], already scaled
        pr[k] -= lr * lkj;              // meaningful for lanes > j; junk elsewhere, never read
      }
    }
#pragma unroll
    for (int k = 0; k < 64; ++k) Lp[tid][k] = pr[k];
#pragma unroll
    for (int k = 0; k < 64; ++k)
      if (k <= tid) A[(size_t)r * D_ + j0 + k] = pr[k];
  }
  __syncthreads();

  if (dosub) {
#pragma unroll
    for (int j = 0; j < 64; ++j) {
      const double wj = x[j] * rsv[j];
      x[j] = wj;
#pragma unroll
      for (int k = j + 1; k < 64; ++k) x[k] -= wj * Lp[k][j];
    }
#pragma unroll
    for (int k = 0; k < 64; ++k) A[(size_t)rsub * D_ + j0 + k] = x[k];
  }
}

// ---------------- kernel 2b: trailing update for panel p, one block per 64x64 tile ----
__global__ __launch_bounds__(256) void chol_trail(double* __restrict__ A, int p) {
  const int j0 = p * 64;
  const int t0 = j0 + 64;
  int b = blockIdx.x, I = 0;
  while (b >= I + 1) { b -= I + 1; ++I; }   // lower tile pair (I,J), J<=I
  const int J = b;
  const int r0 = t0 + I * 64, c0 = t0 + J * 64;
  __shared__ double LR[64][67];
  __shared__ double LC[64][67];
  const int tid = threadIdx.x;
  for (int e = tid; e < 64 * 64; e += 256) {
    int rr = e >> 6, cc = e & 63;
    LR[rr][cc] = A[(size_t)(r0 + rr) * D_ + j0 + cc];
    LC[rr][cc] = A[(size_t)(c0 + rr) * D_ + j0 + cc];
  }
  __syncthreads();
  const int tx = tid & 15, ty = tid >> 4;
  double acc[4][4];
#pragma unroll
  for (int i = 0; i < 4; ++i)
#pragma unroll
    for (int j = 0; j < 4; ++j) acc[i][j] = 0.0;
#pragma unroll 4
  for (int k = 0; k < 64; ++k) {
    double a_[4], b_[4];
#pragma unroll
    for (int i = 0; i < 4; ++i) a_[i] = LR[ty + 16 * i][k];
#pragma unroll
    for (int j = 0; j < 4; ++j) b_[j] = LC[tx + 16 * j][k];
#pragma unroll
    for (int i = 0; i < 4; ++i)
#pragma unroll
      for (int j = 0; j < 4; ++j) acc[i][j] += a_[i] * b_[j];
  }
#pragma unroll
  for (int i = 0; i < 4; ++i) {
    const int grow = r0 + ty + 16 * i;
#pragma unroll
    for (int j = 0; j < 4; ++j) {
      const int gcol = c0 + tx + 16 * j;
      A[(size_t)grow * D_ + gcol] -= acc[i][j];
    }
  }
}

// ---------------- kernel 3: W = L^-1 column c + f16 emit (WbT row-major-T, WbP packed) -
__global__ __launch_bounds__(256) void inv_kernel(const double* __restrict__ L,
                                                  _Float16* __restrict__ WbP,
                                                  _Float16* __restrict__ WbT) {
  const int c = blockIdx.x;
  const int tid = threadIdx.x;
  __shared__ double w[D_];
  __shared__ double rdi[D_];
  __shared__ double rhs[32];
  __shared__ double Ldd[32][33];
  w[tid] = 0.0;
  rdi[tid] = 1.0 / L[(size_t)tid * D_ + tid];
  __syncthreads();
  const int q0 = c >> 5;
  for (int q = q0; q < 8; ++q) {
    const int i0 = q * 32;
    const int ii = tid >> 3, s = tid & 7;
    const int i = i0 + ii;
    double part = 0.0;
    for (int k = c + s; k < i0; k += 8) part += L[(size_t)i * D_ + k] * w[k];
    part += __shfl_xor(part, 1, 64);
    part += __shfl_xor(part, 2, 64);
    part += __shfl_xor(part, 4, 64);
    if (s == 0) rhs[ii] = ((i == c) ? 1.0 : 0.0) - part;
    for (int e = tid; e < 32 * 32; e += 256) {
      int rr = e >> 5, cc = e & 31;
      Ldd[rr][cc] = L[(size_t)(i0 + rr) * D_ + i0 + cc];
    }
    __syncthreads();
    if (tid < 32) {
      double x = rhs[tid];
      double v = 0.0;
      for (int j = 0; j < 32; ++j) {
        double xj = __shfl(x, j, 64);
        double wj = xj * rdi[i0 + j];
        if (tid == j) v = wj;
        if (tid > j) x -= Ldd[tid][j] * wj;
      }
      w[i0 + tid] = v;
    }
    __syncthreads();
  }
  _Float16 h = (_Float16)(float)w[tid];
  WbT[(size_t)c * D_ + tid] = h;   // WbT[k=c][i=tid], coalesced (sig uses this)
  {
    const int g = tid >> 4, lrr = tid & 15;
    const int ks = c >> 5, lqq = (c >> 3) & 3, jj = c & 7;
    WbP[(size_t)(g * 8 + ks) * 512 + (size_t)(lqq * 16 + lrr) * 8 + jj] = h;
  }
}

// ---------------- kernel 5: signatures, normalized, packed MFMA-fragment layout -------
__global__ void sig_kernel(const float* __restrict__ S, const _Float16* __restrict__ WbT,
                           _Float16* __restrict__ sHatP) {
  int c = blockIdx.x, i = threadIdx.x;
  const int g = c >> 4, lr = c & 15;
  const int ks = i >> 5, lq = (i >> 3) & 3, jj = i & 7;
  const size_t off = (size_t)(g * 8 + ks) * 512 + (size_t)(lq * 16 + lr) * 8 + jj;
  if (c >= C_) { sHatP[off] = (_Float16)0.0f; return; }  // pad classes exactly 0
  __shared__ float srow[D_];
  __shared__ float wred[4];
  srow[i] = S[c * D_ + i];
  __syncthreads();
  float t = 0.f;
  for (int k = 0; k < D_; ++k) t += (float)WbT[k * D_ + i] * srow[k];
  float ss = t * t;
#pragma unroll
  for (int d = 1; d < 64; d <<= 1) ss += __shfl_xor(ss, d, 64);
  if ((i & 63) == 0) wred[i >> 6] = ss;
  __syncthreads();
  float tot = wred[0] + wred[1] + wred[2] + wred[3];
  float rn = 1.0f / fmaxf(sqrtf(tot), 1e-12f);
  sHatP[off] = (_Float16)(t * rn);
}

// ---------------- kernel 8: FUSED whiten + GEMM + logsumexp + finalize ----------------
__global__ __launch_bounds__(1024) void ace_kernel(const float* __restrict__ X,
                                                   const float* __restrict__ means,
                                                   const _Float16* __restrict__ WbP,
                                                   const _Float16* __restrict__ sHatP,
                                                   const int* __restrict__ labels,
                                                   float* __restrict__ out,
                                                   double* __restrict__ acc_loss,
                                                   unsigned int* __restrict__ counter) {
  __shared__ __align__(16) char ldsraw[131072];  // phase1: Wsh | phase2: xs | phase3: Bsh[2]
  __shared__ float msh[D_];
  __shared__ float part[64];
  _Float16* const Wsh = (_Float16*)ldsraw;
  char* const xsC = ldsraw;
  _Float16* const Bsh = (_Float16*)ldsraw;       // [2][32768]
  float* const outACE = out + 1;

  const int tid = threadIdx.x;
  const int wid = tid >> 6, l = tid & 63, lr = l & 15, lq = l >> 4;
  const int rowbase = blockIdx.x * 256;
  const int wrow = rowbase + wid * 16;           // this wave's 16-row strip
  const int arow = wrow + lr;                    // A-operand row (global)

  // ---- phase 1: stage WbP (128 KB) ----
  if (tid < 256) msh[tid] = means[tid];
#pragma unroll
  for (int s = 0; s < 8; ++s) {
    const int off = (wid * 8 + s) * 512;
    __builtin_amdgcn_global_load_lds(
        (const __attribute__((address_space(1))) unsigned int*)(WbP + off + l * 8),
        (__attribute__((address_space(3))) unsigned int*)(Wsh + off), 16, 0, 0);
  }
  __syncthreads();

  // ---- phase 2: whiten (X - m) @ W^T for this wave's 16 rows ----
  f16x8 af[8];
#pragma unroll
  for (int ks = 0; ks < 8; ++ks) {
    const float* xp = X + (size_t)arow * D_ + lq * 8 + ks * 32;
    const float4 x0 = *(const float4*)(xp);
    const float4 x1 = *(const float4*)(xp + 4);
    const int mb = lq * 8 + ks * 32;
    af[ks][0] = (_Float16)(x0.x - msh[mb + 0]);
    af[ks][1] = (_Float16)(x0.y - msh[mb + 1]);
    af[ks][2] = (_Float16)(x0.z - msh[mb + 2]);
    af[ks][3] = (_Float16)(x0.w - msh[mb + 3]);
    af[ks][4] = (_Float16)(x1.x - msh[mb + 4]);
    af[ks][5] = (_Float16)(x1.y - msh[mb + 5]);
    af[ks][6] = (_Float16)(x1.z - msh[mb + 6]);
    af[ks][7] = (_Float16)(x1.w - msh[mb + 7]);
  }
  f32x4 wacc[16];
#pragma unroll
  for (int u = 0; u < 16; ++u) wacc[u] = (f32x4){0.f, 0.f, 0.f, 0.f};
  {
    const _Float16* wb = Wsh + (size_t)l * 8;
#pragma unroll
    for (int ks = 0; ks < 8; ++ks) {
#pragma unroll
      for (int u = 0; u < 16; ++u) {
        f16x8 bf = *(const f16x8*)(wb + (u * 8 + ks) * 512);
        wacc[u] = __builtin_amdgcn_mfma_f32_16x16x32_f16(af[ks], bf, wacc[u], 0, 0, 0);
      }
    }
  }
  // row norms (C-layout rows) -> rx in registers
  float ss[4] = {0.f, 0.f, 0.f, 0.f};
#pragma unroll
  for (int u = 0; u < 16; ++u)
#pragma unroll
    for (int j = 0; j < 4; ++j) ss[j] += wacc[u][j] * wacc[u][j];
#pragma unroll
  for (int d = 1; d < 16; d <<= 1) {
#pragma unroll
    for (int j = 0; j < 4; ++j) ss[j] += __shfl_xor(ss[j], d, 64);
  }
  float rx[4];
#pragma unroll
  for (int j = 0; j < 4; ++j) rx[j] = 1.0f / fmaxf(sqrtf(ss[j]), 1e-12f);

  __syncthreads();   // all waves done reading Wsh

  // ---- write whitened strip to LDS (swizzled), re-read as A-fragments ----
#pragma unroll
  for (int u = 0; u < 16; ++u) {
#pragma unroll
    for (int j = 0; j < 4; ++j) {
      const int rowl = wid * 16 + lq * 4 + j;
      const int byte = (rowl * 512 + (u * 16 + lr) * 2) ^ ((rowl & 7) << 4);
      *(_Float16*)(xsC + byte) = (_Float16)wacc[u][j];
    }
  }
  __syncthreads();   // writes visible
  f16x8 a[8];
  {
    const int rowA = wid * 16 + lr;
#pragma unroll
    for (int ks = 0; ks < 8; ++ks) {
      const int byte = (rowA * 512 + ks * 64 + lq * 16) ^ ((rowA & 7) << 4);
      a[ks] = *(const f16x8*)(xsC + byte);
    }
  }
  __syncthreads();   // all A-frag reads done before Bsh staging overwrites

  // ---- phase 3: main GEMM over classes, LDS B double-buffer, counted vmcnt ----
  int lab[4]; float ssum[4], num[4];
#pragma unroll
  for (int j = 0; j < 4; ++j) {
    lab[j] = labels[wrow + lq * 4 + j];
    ssum[j] = 0.f; num[j] = 0.f;
  }

#define STAGE(bufi, chi) do {                                                        \
    const _Float16* _src = sHatP + (size_t)(chi) * 32768;                            \
    _Float16* _dst = Bsh + (size_t)(bufi) * 32768;                                   \
    _Pragma("unroll")                                                                \
    for (int _s = 0; _s < 4; ++_s) {                                                 \
      const int _off = wid * 2048 + _s * 512;                                        \
      __builtin_amdgcn_global_load_lds(                                              \
          (const __attribute__((address_space(1))) unsigned int*)(_src + _off + l * 8), \
          (__attribute__((address_space(3))) unsigned int*)(_dst + _off), 16, 0, 0); \
    } } while (0)

  float* const outrow = outACE + (size_t)(wrow + lq * 4) * C_;

  STAGE(0, 0);
  __syncthreads();                              // prologue: full drain once
  int buf = 0;
  for (int ch = 0; ch < 8; ++ch) {
    if (ch < 7) {
      STAGE(buf ^ 1, ch + 1);
      __builtin_amdgcn_sched_barrier(0);        // pin stage loads before compute/stores
    }
    const _Float16* bb = Bsh + (size_t)buf * 32768 + (size_t)l * 8;
    f32x4 acc[8];
#pragma unroll
    for (int t = 0; t < 8; ++t) acc[t] = (f32x4){0.f, 0.f, 0.f, 0.f};
#pragma unroll
    for (int ks = 0; ks < 8; ++ks) {
#pragma unroll
      for (int t = 0; t < 8; ++t) {
        f16x8 bf = *(const f16x8*)(bb + (t * 8 + ks) * 512);
        acc[t] = __builtin_amdgcn_mfma_f32_16x16x32_f16(a[ks], bf, acc[t], 0, 0, 0);
      }
    }
#pragma unroll
    for (int t = 0; t < 8; ++t) {
      const int col = ch * 128 + t * 16 + lr;
      const bool valid = (col < C_);
#pragma unroll
      for (int j = 0; j < 4; ++j) {
        float v = acc[t][j] * rx[j];
        if (valid) outrow[(size_t)j * C_ + col] = v;
        ssum[j] += __expf(v - 1.0f);
        num[j] = (col == lab[j]) ? v : num[j];
      }
    }
    if (ch < 7) {
      __builtin_amdgcn_sched_barrier(0);
      asm volatile("s_waitcnt vmcnt(32)" ::: "memory");  // retires the 4 stage loads
      __builtin_amdgcn_s_barrier();
      __builtin_amdgcn_sched_barrier(0);
    }
    buf ^= 1;
  }
#undef STAGE

#pragma unroll
  for (int d2 = 1; d2 < 16; d2 <<= 1) {
#pragma unroll
    for (int j = 0; j < 4; ++j) {
      ssum[j] += __shfl_xor(ssum[j], d2, 64);
      num[j]  += __shfl_xor(num[j], d2, 64);
    }
  }
  if (lr == 0) {
    const float padcorr = 24.0f * __expf(-1.0f);
    float contrib = 0.f;
#pragma unroll
    for (int j = 0; j < 4; ++j)
      contrib += num[j] - (1.0f + __logf(ssum[j] - padcorr));
    part[wid * 4 + lq] = contrib;
  }
  __syncthreads();
  if (tid == 0) {
    float s = 0.f;
#pragma unroll
    for (int p2 = 0; p2 < 64; ++p2) s += part[p2];
    atomicAdd(acc_loss, (double)s);
    __threadfence();
    unsigned int old = atomicAdd(counter, 1u);
    if (old == (unsigned int)(gridDim.x - 1)) {
      __threadfence();
      double tot = atomicAdd(acc_loss, 0.0);    // coherent read of final sum
      out[0] = (float)(-tot / (double)B_);
    }
  }
}

extern "C" void kernel_launch(void* const* d_in, const int* in_sizes, int n_in,
                              void* d_out, int out_size, void* d_ws, size_t ws_size,
                              hipStream_t stream) {
  const float* X      = (const float*)d_in[0];
  const int*   labels = (const int*)d_in[1];
  const float* S      = (const float*)d_in[2];
  const float* means  = (const float*)d_in[3];
  const float* bc     = (const float*)d_in[4];
  float* out = (float*)d_out;

  char* w = (char*)d_ws;
  double*       acc   = (double*)(w + 0);
  unsigned int* cnt   = (unsigned int*)(w + 128);
  double*       C64   = (double*)(w + 256);       // 512 KB
  _Float16*     WbP   = (_Float16*)(w + 524544);  // 128 KB packed B (whiten)
  _Float16*     WbT   = (_Float16*)(w + 655616);  // 128 KB (sig)
  _Float16*     sHatP = (_Float16*)(w + 786688);  // 512 KB packed (1024 classes)

  cov_kernel<<<64, 256, 0, stream>>>(bc, C64, acc, cnt);
  for (int p = 0; p < 4; ++p) {
    chol_panel<<<1, 256, 0, stream>>>(C64, p);
    int nt = 3 - p;
    if (nt > 0) chol_trail<<<nt * (nt + 1) / 2, 256, 0, stream>>>(C64, p);
  }
  inv_kernel<<<256, 256, 0, stream>>>(C64, WbP, WbT);
  sig_kernel<<<1024, 256, 0, stream>>>(S, WbT, sHatP);
  ace_kernel<<<256, 1024, 0, stream>>>(X, means, WbP, sHatP, labels, out, acc, cnt);
}

// Round 12
// 1008.048 us; speedup vs baseline: 1.0711x; 1.0711x over previous
//
#include <hip/hip_runtime.h>
#include <hip/hip_bf16.h>
#include <math.h>

#define D_ 256
#define B_ 65536
#define C_ 1000

typedef _Float16 f16x8 __attribute__((ext_vector_type(8)));
typedef float f32x4 __attribute__((ext_vector_type(4)));

// ---------------- kernel 1: cov = bc @ bc^T in fp64, LDS-tiled; zeroes acc+counter ----
__global__ __launch_bounds__(256) void cov_kernel(const float* __restrict__ bc,
                                                  double* __restrict__ C64,
                                                  double* __restrict__ acc,
                                                  unsigned int* __restrict__ counter) {
  __shared__ float Ash[32][260];
  __shared__ float Bsh2[32][260];
  const int b = blockIdx.x, bi = b >> 3, bj = b & 7;
  const int e = threadIdx.x;
  if (b == 0 && e == 0) { *acc = 0.0; *counter = 0u; }
#pragma unroll
  for (int s = 0; s < 32; ++s) {
    int lin = s * 256 + e;
    int rr = lin >> 8, cc = lin & 255;
    Ash[rr][cc] = bc[(bi * 32 + rr) * 256 + cc];
    Bsh2[rr][cc] = bc[(bj * 32 + rr) * 256 + cc];
  }
  __syncthreads();
  const int tx = e & 15, ty = e >> 4;
  double a00 = 0, a01 = 0, a10 = 0, a11 = 0;
#pragma unroll 8
  for (int k = 0; k < 256; ++k) {
    double ar0 = (double)Ash[ty][k], ar1 = (double)Ash[ty + 16][k];
    double br0 = (double)Bsh2[tx][k], br1 = (double)Bsh2[tx + 16][k];
    a00 += ar0 * br0; a01 += ar0 * br1;
    a10 += ar1 * br0; a11 += ar1 * br1;
  }
  const int r0 = bi * 32, c0 = bj * 32;
  C64[(size_t)(r0 + ty) * D_ + c0 + tx] = a00;
  C64[(size_t)(r0 + ty) * D_ + c0 + tx + 16] = a01;
  C64[(size_t)(r0 + ty + 16) * D_ + c0 + tx] = a10;
  C64[(size_t)(r0 + ty + 16) * D_ + c0 + tx + 16] = a11;
}

// ---------------- kernel 2a: panel factor v4 — v3 with DISJOINT register liveness -----
// Wave 0 factors the 64x64 diag block in registers via shfl (no barriers). ONE
// __syncthreads. THEN threads 64..255 load + forward-substitute their off-panel row
// (x[64] live only after the barrier -> allocator overlays it with wave0's pr[64];
// v3's prefetch made both live simultaneously -> 256 VGPR cap + scratch spill).
__global__ __launch_bounds__(256, 1) void chol_panel(double* __restrict__ A, int p) {
  const int j0 = p * 64;
  const int tid = threadIdx.x;
  __shared__ double Lp[64][65];
  __shared__ double rsv[64];

  if (tid < 64) {                       // wave 0: factor 64x64 diag block
    const int r = j0 + tid;
    double pr[64];
#pragma unroll
    for (int k = 0; k < 64; ++k) pr[k] = A[(size_t)r * D_ + j0 + k];
#pragma unroll
    for (int j = 0; j < 64; ++j) {
      const double d2 = __shfl(pr[j], j, 64);
      double rs = (double)rsqrtf((float)d2);
      rs = rs * (1.5 - 0.5 * d2 * rs * rs);
      rs = rs * (1.5 - 0.5 * d2 * rs * rs);
      const double lr = pr[j] * rs;     // lane j: sqrt(d2); lanes>j: L_rj; lanes<j: junk
      pr[j] = lr;
      if (tid == j) rsv[j] = rs;
#pragma unroll
      for (int k = j + 1; k < 64; ++k) {
        const double lkj = __shfl(lr, k, 64);   // L[j0+k][col], already scaled
        pr[k] -= lr * lkj;              // meaningful for lanes > j; junk elsewhere
      }
    }
#pragma unroll
    for (int k = 0; k < 64; ++k) Lp[tid][k] = pr[k];
#pragma unroll
    for (int k = 0; k < 64; ++k)
      if (k <= tid) A[(size_t)r * D_ + j0 + k] = pr[k];
  }
  __syncthreads();

  const int rsub = j0 + tid;
  if (tid >= 64 && rsub < D_) {         // off-panel rows: independent fwd substitution
    double x[64];
#pragma unroll
    for (int k = 0; k < 64; ++k) x[k] = A[(size_t)rsub * D_ + j0 + k];
#pragma unroll
    for (int j = 0; j < 64; ++j) {
      const double wj = x[j] * rsv[j];
      x[j] = wj;
#pragma unroll
      for (int k = j + 1; k < 64; ++k) x[k] -= wj * Lp[k][j];
    }
#pragma unroll
    for (int k = 0; k < 64; ++k) A[(size_t)rsub * D_ + j0 + k] = x[k];
  }
}

// ---------------- kernel 2b: trailing update for panel p, one block per 64x64 tile ----
__global__ __launch_bounds__(256) void chol_trail(double* __restrict__ A, int p) {
  const int j0 = p * 64;
  const int t0 = j0 + 64;
  int b = blockIdx.x, I = 0;
  while (b >= I + 1) { b -= I + 1; ++I; }   // lower tile pair (I,J), J<=I
  const int J = b;
  const int r0 = t0 + I * 64, c0 = t0 + J * 64;
  __shared__ double LR[64][67];
  __shared__ double LC[64][67];
  const int tid = threadIdx.x;
  for (int e = tid; e < 64 * 64; e += 256) {
    int rr = e >> 6, cc = e & 63;
    LR[rr][cc] = A[(size_t)(r0 + rr) * D_ + j0 + cc];
    LC[rr][cc] = A[(size_t)(c0 + rr) * D_ + j0 + cc];
  }
  __syncthreads();
  const int tx = tid & 15, ty = tid >> 4;
  double acc[4][4];
#pragma unroll
  for (int i = 0; i < 4; ++i)
#pragma unroll
    for (int j = 0; j < 4; ++j) acc[i][j] = 0.0;
#pragma unroll 4
  for (int k = 0; k < 64; ++k) {
    double a_[4], b_[4];
#pragma unroll
    for (int i = 0; i < 4; ++i) a_[i] = LR[ty + 16 * i][k];
#pragma unroll
    for (int j = 0; j < 4; ++j) b_[j] = LC[tx + 16 * j][k];
#pragma unroll
    for (int i = 0; i < 4; ++i)
#pragma unroll
      for (int j = 0; j < 4; ++j) acc[i][j] += a_[i] * b_[j];
  }
#pragma unroll
  for (int i = 0; i < 4; ++i) {
    const int grow = r0 + ty + 16 * i;
#pragma unroll
    for (int j = 0; j < 4; ++j) {
      const int gcol = c0 + tx + 16 * j;
      A[(size_t)grow * D_ + gcol] -= acc[i][j];
    }
  }
}

// ---------------- kernel 3: W = L^-1 column c + f16 emit (WbT row-major-T, WbP packed) -
__global__ __launch_bounds__(256) void inv_kernel(const double* __restrict__ L,
                                                  _Float16* __restrict__ WbP,
                                                  _Float16* __restrict__ WbT) {
  const int c = blockIdx.x;
  const int tid = threadIdx.x;
  __shared__ double w[D_];
  __shared__ double rdi[D_];
  __shared__ double rhs[32];
  __shared__ double Ldd[32][33];
  w[tid] = 0.0;
  rdi[tid] = 1.0 / L[(size_t)tid * D_ + tid];
  __syncthreads();
  const int q0 = c >> 5;
  for (int q = q0; q < 8; ++q) {
    const int i0 = q * 32;
    const int ii = tid >> 3, s = tid & 7;
    const int i = i0 + ii;
    double part = 0.0;
    for (int k = c + s; k < i0; k += 8) part += L[(size_t)i * D_ + k] * w[k];
    part += __shfl_xor(part, 1, 64);
    part += __shfl_xor(part, 2, 64);
    part += __shfl_xor(part, 4, 64);
    if (s == 0) rhs[ii] = ((i == c) ? 1.0 : 0.0) - part;
    for (int e = tid; e < 32 * 32; e += 256) {
      int rr = e >> 5, cc = e & 31;
      Ldd[rr][cc] = L[(size_t)(i0 + rr) * D_ + i0 + cc];
    }
    __syncthreads();
    if (tid < 32) {
      double x = rhs[tid];
      double v = 0.0;
      for (int j = 0; j < 32; ++j) {
        double xj = __shfl(x, j, 64);
        double wj = xj * rdi[i0 + j];
        if (tid == j) v = wj;
        if (tid > j) x -= Ldd[tid][j] * wj;
      }
      w[i0 + tid] = v;
    }
    __syncthreads();
  }
  _Float16 h = (_Float16)(float)w[tid];
  WbT[(size_t)c * D_ + tid] = h;   // WbT[k=c][i=tid], coalesced (sig uses this)
  {
    const int g = tid >> 4, lrr = tid & 15;
    const int ks = c >> 5, lqq = (c >> 3) & 3, jj = c & 7;
    WbP[(size_t)(g * 8 + ks) * 512 + (size_t)(lqq * 16 + lrr) * 8 + jj] = h;
  }
}

// ---------------- kernel 5: signatures, normalized, packed MFMA-fragment layout -------
__global__ void sig_kernel(const float* __restrict__ S, const _Float16* __restrict__ WbT,
                           _Float16* __restrict__ sHatP) {
  int c = blockIdx.x, i = threadIdx.x;
  const int g = c >> 4, lr = c & 15;
  const int ks = i >> 5, lq = (i >> 3) & 3, jj = i & 7;
  const size_t off = (size_t)(g * 8 + ks) * 512 + (size_t)(lq * 16 + lr) * 8 + jj;
  if (c >= C_) { sHatP[off] = (_Float16)0.0f; return; }  // pad classes exactly 0
  __shared__ float srow[D_];
  __shared__ float wred[4];
  srow[i] = S[c * D_ + i];
  __syncthreads();
  float t = 0.f;
  for (int k = 0; k < D_; ++k) t += (float)WbT[k * D_ + i] * srow[k];
  float ss = t * t;
#pragma unroll
  for (int d = 1; d < 64; d <<= 1) ss += __shfl_xor(ss, d, 64);
  if ((i & 63) == 0) wred[i >> 6] = ss;
  __syncthreads();
  float tot = wred[0] + wred[1] + wred[2] + wred[3];
  float rn = 1.0f / fmaxf(sqrtf(tot), 1e-12f);
  sHatP[off] = (_Float16)(t * rn);
}

// ---------------- kernel 8: FUSED whiten + GEMM + logsumexp + finalize ----------------
__global__ __launch_bounds__(1024) void ace_kernel(const float* __restrict__ X,
                                                   const float* __restrict__ means,
                                                   const _Float16* __restrict__ WbP,
                                                   const _Float16* __restrict__ sHatP,
                                                   const int* __restrict__ labels,
                                                   float* __restrict__ out,
                                                   double* __restrict__ acc_loss,
                                                   unsigned int* __restrict__ counter) {
  __shared__ __align__(16) char ldsraw[131072];  // phase1: Wsh | phase2: xs | phase3: Bsh[2]
  __shared__ float msh[D_];
  __shared__ float part[64];
  _Float16* const Wsh = (_Float16*)ldsraw;
  char* const xsC = ldsraw;
  _Float16* const Bsh = (_Float16*)ldsraw;       // [2][32768]
  float* const outACE = out + 1;

  const int tid = threadIdx.x;
  const int wid = tid >> 6, l = tid & 63, lr = l & 15, lq = l >> 4;
  const int rowbase = blockIdx.x * 256;
  const int wrow = rowbase + wid * 16;           // this wave's 16-row strip
  const int arow = wrow + lr;                    // A-operand row (global)

  // ---- phase 1: stage WbP (128 KB) ----
  if (tid < 256) msh[tid] = means[tid];
#pragma unroll
  for (int s = 0; s < 8; ++s) {
    const int off = (wid * 8 + s) * 512;
    __builtin_amdgcn_global_load_lds(
        (const __attribute__((address_space(1))) unsigned int*)(WbP + off + l * 8),
        (__attribute__((address_space(3))) unsigned int*)(Wsh + off), 16, 0, 0);
  }
  __syncthreads();

  // ---- phase 2: whiten (X - m) @ W^T for this wave's 16 rows ----
  f16x8 af[8];
#pragma unroll
  for (int ks = 0; ks < 8; ++ks) {
    const float* xp = X + (size_t)arow * D_ + lq * 8 + ks * 32;
    const float4 x0 = *(const float4*)(xp);
    const float4 x1 = *(const float4*)(xp + 4);
    const int mb = lq * 8 + ks * 32;
    af[ks][0] = (_Float16)(x0.x - msh[mb + 0]);
    af[ks][1] = (_Float16)(x0.y - msh[mb + 1]);
    af[ks][2] = (_Float16)(x0.z - msh[mb + 2]);
    af[ks][3] = (_Float16)(x0.w - msh[mb + 3]);
    af[ks][4] = (_Float16)(x1.x - msh[mb + 4]);
    af[ks][5] = (_Float16)(x1.y - msh[mb + 5]);
    af[ks][6] = (_Float16)(x1.z - msh[mb + 6]);
    af[ks][7] = (_Float16)(x1.w - msh[mb + 7]);
  }
  f32x4 wacc[16];
#pragma unroll
  for (int u = 0; u < 16; ++u) wacc[u] = (f32x4){0.f, 0.f, 0.f, 0.f};
  {
    const _Float16* wb = Wsh + (size_t)l * 8;
#pragma unroll
    for (int ks = 0; ks < 8; ++ks) {
#pragma unroll
      for (int u = 0; u < 16; ++u) {
        f16x8 bf = *(const f16x8*)(wb + (u * 8 + ks) * 512);
        wacc[u] = __builtin_amdgcn_mfma_f32_16x16x32_f16(af[ks], bf, wacc[u], 0, 0, 0);
      }
    }
  }
  // row norms (C-layout rows) -> rx in registers
  float ss[4] = {0.f, 0.f, 0.f, 0.f};
#pragma unroll
  for (int u = 0; u < 16; ++u)
#pragma unroll
    for (int j = 0; j < 4; ++j) ss[j] += wacc[u][j] * wacc[u][j];
#pragma unroll
  for (int d = 1; d < 16; d <<= 1) {
#pragma unroll
    for (int j = 0; j < 4; ++j) ss[j] += __shfl_xor(ss[j], d, 64);
  }
  float rx[4];
#pragma unroll
  for (int j = 0; j < 4; ++j) rx[j] = 1.0f / fmaxf(sqrtf(ss[j]), 1e-12f);

  __syncthreads();   // all waves done reading Wsh

  // ---- write whitened strip to LDS (swizzled), re-read as A-fragments ----
#pragma unroll
  for (int u = 0; u < 16; ++u) {
#pragma unroll
    for (int j = 0; j < 4; ++j) {
      const int rowl = wid * 16 + lq * 4 + j;
      const int byte = (rowl * 512 + (u * 16 + lr) * 2) ^ ((rowl & 7) << 4);
      *(_Float16*)(xsC + byte) = (_Float16)wacc[u][j];
    }
  }
  __syncthreads();   // writes visible
  f16x8 a[8];
  {
    const int rowA = wid * 16 + lr;
#pragma unroll
    for (int ks = 0; ks < 8; ++ks) {
      const int byte = (rowA * 512 + ks * 64 + lq * 16) ^ ((rowA & 7) << 4);
      a[ks] = *(const f16x8*)(xsC + byte);
    }
  }
  __syncthreads();   // all A-frag reads done before Bsh staging overwrites

  // ---- phase 3: main GEMM over classes, LDS B double-buffer, counted vmcnt ----
  int lab[4]; float ssum[4], num[4];
#pragma unroll
  for (int j = 0; j < 4; ++j) {
    lab[j] = labels[wrow + lq * 4 + j];
    ssum[j] = 0.f; num[j] = 0.f;
  }

#define STAGE(bufi, chi) do {                                                        \
    const _Float16* _src = sHatP + (size_t)(chi) * 32768;                            \
    _Float16* _dst = Bsh + (size_t)(bufi) * 32768;                                   \
    _Pragma("unroll")                                                                \
    for (int _s = 0; _s < 4; ++_s) {                                                 \
      const int _off = wid * 2048 + _s * 512;                                        \
      __builtin_amdgcn_global_load_lds(                                              \
          (const __attribute__((address_space(1))) unsigned int*)(_src + _off + l * 8), \
          (__attribute__((address_space(3))) unsigned int*)(_dst + _off), 16, 0, 0); \
    } } while (0)

  float* const outrow = outACE + (size_t)(wrow + lq * 4) * C_;

  STAGE(0, 0);
  __syncthreads();                              // prologue: full drain once
  int buf = 0;
  for (int ch = 0; ch < 8; ++ch) {
    if (ch < 7) {
      STAGE(buf ^ 1, ch + 1);
      __builtin_amdgcn_sched_barrier(0);        // pin stage loads before compute/stores
    }
    const _Float16* bb = Bsh + (size_t)buf * 32768 + (size_t)l * 8;
    f32x4 acc[8];
#pragma unroll
    for (int t = 0; t < 8; ++t) acc[t] = (f32x4){0.f, 0.f, 0.f, 0.f};
#pragma unroll
    for (int ks = 0; ks < 8; ++ks) {
#pragma unroll
      for (int t = 0; t < 8; ++t) {
        f16x8 bf = *(const f16x8*)(bb + (t * 8 + ks) * 512);
        acc[t] = __builtin_amdgcn_mfma_f32_16x16x32_f16(a[ks], bf, acc[t], 0, 0, 0);
      }
    }
#pragma unroll
    for (int t = 0; t < 8; ++t) {
      const int col = ch * 128 + t * 16 + lr;
      const bool valid = (col < C_);
#pragma unroll
      for (int j = 0; j < 4; ++j) {
        float v = acc[t][j] * rx[j];
        if (valid) outrow[(size_t)j * C_ + col] = v;
        ssum[j] += __expf(v - 1.0f);
        num[j] = (col == lab[j]) ? v : num[j];
      }
    }
    if (ch < 7) {
      __builtin_amdgcn_sched_barrier(0);
      asm volatile("s_waitcnt vmcnt(32)" ::: "memory");  // retires the 4 stage loads
      __builtin_amdgcn_s_barrier();
      __builtin_amdgcn_sched_barrier(0);
    }
    buf ^= 1;
  }
#undef STAGE

#pragma unroll
  for (int d2 = 1; d2 < 16; d2 <<= 1) {
#pragma unroll
    for (int j = 0; j < 4; ++j) {
      ssum[j] += __shfl_xor(ssum[j], d2, 64);
      num[j]  += __shfl_xor(num[j], d2, 64);
    }
  }
  if (lr == 0) {
    const float padcorr = 24.0f * __expf(-1.0f);
    float contrib = 0.f;
#pragma unroll
    for (int j = 0; j < 4; ++j)
      contrib += num[j] - (1.0f + __logf(ssum[j] - padcorr));
    part[wid * 4 + lq] = contrib;
  }
  __syncthreads();
  if (tid == 0) {
    float s = 0.f;
#pragma unroll
    for (int p2 = 0; p2 < 64; ++p2) s += part[p2];
    atomicAdd(acc_loss, (double)s);
    __threadfence();
    unsigned int old = atomicAdd(counter, 1u);
    if (old == (unsigned int)(gridDim.x - 1)) {
      __threadfence();
      double tot = atomicAdd(acc_loss, 0.0);    // coherent read of final sum
      out[0] = (float)(-tot / (double)B_);
    }
  }
}

extern "C" void kernel_launch(void* const* d_in, const int* in_sizes, int n_in,
                              void* d_out, int out_size, void* d_ws, size_t ws_size,
                              hipStream_t stream) {
  const float* X      = (const float*)d_in[0];
  const int*   labels = (const int*)d_in[1];
  const float* S      = (const float*)d_in[2];
  const float* means  = (const float*)d_in[3];
  const float* bc     = (const float*)d_in[4];
  float* out = (float*)d_out;

  char* w = (char*)d_ws;
  double*       acc   = (double*)(w + 0);
  unsigned int* cnt   = (unsigned int*)(w + 128);
  double*       C64   = (double*)(w + 256);       // 512 KB
  _Float16*     WbP   = (_Float16*)(w + 524544);  // 128 KB packed B (whiten)
  _Float16*     WbT   = (_Float16*)(w + 655616);  // 128 KB (sig)
  _Float16*     sHatP = (_Float16*)(w + 786688);  // 512 KB packed (1024 classes)

  cov_kernel<<<64, 256, 0, stream>>>(bc, C64, acc, cnt);
  for (int p = 0; p < 4; ++p) {
    chol_panel<<<1, 256, 0, stream>>>(C64, p);
    int nt = 3 - p;
    if (nt > 0) chol_trail<<<nt * (nt + 1) / 2, 256, 0, stream>>>(C64, p);
  }
  inv_kernel<<<256, 256, 0, stream>>>(C64, WbP, WbT);
  sig_kernel<<<1024, 256, 0, stream>>>(S, WbT, sHatP);
  ace_kernel<<<256, 1024, 0, stream>>>(X, means, WbP, sHatP, labels, out, acc, cnt);
}

// Round 13
// 358.233 us; speedup vs baseline: 3.0139x; 2.8139x over previous
//
#include <hip/hip_runtime.h>
#include <hip/hip_bf16.h>
#include <math.h>

#define D_ 256
#define B_ 65536
#define C_ 1000

typedef _Float16 f16x8 __attribute__((ext_vector_type(8)));
typedef float f32x4 __attribute__((ext_vector_type(4)));

// ---------------- kernel 1: cov = bc @ bc^T in fp64, LDS-tiled; zeroes acc+counter ----
__global__ __launch_bounds__(256) void cov_kernel(const float* __restrict__ bc,
                                                  double* __restrict__ C64,
                                                  double* __restrict__ acc,
                                                  unsigned int* __restrict__ counter) {
  __shared__ float Ash[32][260];
  __shared__ float Bsh2[32][260];
  const int b = blockIdx.x, bi = b >> 3, bj = b & 7;
  const int e = threadIdx.x;
  if (b == 0 && e == 0) { *acc = 0.0; *counter = 0u; }
#pragma unroll
  for (int s = 0; s < 32; ++s) {
    int lin = s * 256 + e;
    int rr = lin >> 8, cc = lin & 255;
    Ash[rr][cc] = bc[(bi * 32 + rr) * 256 + cc];
    Bsh2[rr][cc] = bc[(bj * 32 + rr) * 256 + cc];
  }
  __syncthreads();
  const int tx = e & 15, ty = e >> 4;
  double a00 = 0, a01 = 0, a10 = 0, a11 = 0;
#pragma unroll 8
  for (int k = 0; k < 256; ++k) {
    double ar0 = (double)Ash[ty][k], ar1 = (double)Ash[ty + 16][k];
    double br0 = (double)Bsh2[tx][k], br1 = (double)Bsh2[tx + 16][k];
    a00 += ar0 * br0; a01 += ar0 * br1;
    a10 += ar1 * br0; a11 += ar1 * br1;
  }
  const int r0 = bi * 32, c0 = bj * 32;
  C64[(size_t)(r0 + ty) * D_ + c0 + tx] = a00;
  C64[(size_t)(r0 + ty) * D_ + c0 + tx + 16] = a01;
  C64[(size_t)(r0 + ty + 16) * D_ + c0 + tx] = a10;
  C64[(size_t)(r0 + ty + 16) * D_ + c0 + tx + 16] = a11;
}

// ---------------- kernel 2a: factor panel p (64 cols) — R10 version (PROVEN) ----------
// raw[buf][k] holds the PRE-SCALE column-j value of panel row j0+k. Every lane
// redundantly computes rs = rsqrt(d2) (fp32 seed + 2 fp64 Newton steps).
// One barrier per column. Small per-thread arrays (pr[64] only for panel rows).
__global__ __launch_bounds__(256, 1) void chol_panel(double* __restrict__ A, int p) {
  const int j0 = p * 64;
  const int r = threadIdx.x;
  __shared__ double raw[2][64];
  double pr[64];
  const bool act = (r >= j0);
  const bool inpanel = act && (r < j0 + 64);
  if (act) {
#pragma unroll
    for (int k = 0; k < 64; ++k) pr[k] = A[(size_t)r * D_ + j0 + k];
  }
  if (inpanel) raw[0][r - j0] = pr[0];
  __syncthreads();
#pragma unroll
  for (int j = 0; j < 64; ++j) {
    const int col = j0 + j;
    const double d2 = raw[j & 1][j];
    double rs = (double)rsqrtf((float)d2);
    rs = rs * (1.5 - 0.5 * d2 * rs * rs);
    rs = rs * (1.5 - 0.5 * d2 * rs * rs);
    if (r >= col) {
      const double lr_ = pr[j] * rs;   // diag row: d2*rs = sqrt(d2)
      pr[j] = lr_;
#pragma unroll
      for (int k = j + 1; k < 64; ++k) pr[k] -= lr_ * (raw[j & 1][k] * rs);
    }
    if (j < 63) {
      if (r > col && r < j0 + 64) raw[(j + 1) & 1][r - j0] = pr[j + 1];
    }
    __syncthreads();
  }
  if (act) {
    const int kmax = (r - j0 < 63) ? (r - j0) : 63;
#pragma unroll
    for (int k = 0; k < 64; ++k)
      if (k <= kmax) A[(size_t)r * D_ + j0 + k] = pr[k];
  }
}

// ---------------- kernel 2b: trailing update for panel p, one block per 64x64 tile ----
__global__ __launch_bounds__(256) void chol_trail(double* __restrict__ A, int p) {
  const int j0 = p * 64;
  const int t0 = j0 + 64;
  int b = blockIdx.x, I = 0;
  while (b >= I + 1) { b -= I + 1; ++I; }   // lower tile pair (I,J), J<=I
  const int J = b;
  const int r0 = t0 + I * 64, c0 = t0 + J * 64;
  __shared__ double LR[64][67];
  __shared__ double LC[64][67];
  const int tid = threadIdx.x;
  for (int e = tid; e < 64 * 64; e += 256) {
    int rr = e >> 6, cc = e & 63;
    LR[rr][cc] = A[(size_t)(r0 + rr) * D_ + j0 + cc];
    LC[rr][cc] = A[(size_t)(c0 + rr) * D_ + j0 + cc];
  }
  __syncthreads();
  const int tx = tid & 15, ty = tid >> 4;
  double acc[4][4];
#pragma unroll
  for (int i = 0; i < 4; ++i)
#pragma unroll
    for (int j = 0; j < 4; ++j) acc[i][j] = 0.0;
#pragma unroll 4
  for (int k = 0; k < 64; ++k) {
    double a_[4], b_[4];
#pragma unroll
    for (int i = 0; i < 4; ++i) a_[i] = LR[ty + 16 * i][k];
#pragma unroll
    for (int j = 0; j < 4; ++j) b_[j] = LC[tx + 16 * j][k];
#pragma unroll
    for (int i = 0; i < 4; ++i)
#pragma unroll
      for (int j = 0; j < 4; ++j) acc[i][j] += a_[i] * b_[j];
  }
#pragma unroll
  for (int i = 0; i < 4; ++i) {
    const int grow = r0 + ty + 16 * i;
#pragma unroll
    for (int j = 0; j < 4; ++j) {
      const int gcol = c0 + tx + 16 * j;
      A[(size_t)grow * D_ + gcol] -= acc[i][j];
    }
  }
}

// ---------------- kernel 3: W = L^-1 column c + f16 emit (WbT row-major-T, WbP packed) -
__global__ __launch_bounds__(256) void inv_kernel(const double* __restrict__ L,
                                                  _Float16* __restrict__ WbP,
                                                  _Float16* __restrict__ WbT) {
  const int c = blockIdx.x;
  const int tid = threadIdx.x;
  __shared__ double w[D_];
  __shared__ double rdi[D_];
  __shared__ double rhs[32];
  __shared__ double Ldd[32][33];
  w[tid] = 0.0;
  rdi[tid] = 1.0 / L[(size_t)tid * D_ + tid];
  __syncthreads();
  const int q0 = c >> 5;
  for (int q = q0; q < 8; ++q) {
    const int i0 = q * 32;
    const int ii = tid >> 3, s = tid & 7;
    const int i = i0 + ii;
    double part = 0.0;
    for (int k = c + s; k < i0; k += 8) part += L[(size_t)i * D_ + k] * w[k];
    part += __shfl_xor(part, 1, 64);
    part += __shfl_xor(part, 2, 64);
    part += __shfl_xor(part, 4, 64);
    if (s == 0) rhs[ii] = ((i == c) ? 1.0 : 0.0) - part;
    for (int e = tid; e < 32 * 32; e += 256) {
      int rr = e >> 5, cc = e & 31;
      Ldd[rr][cc] = L[(size_t)(i0 + rr) * D_ + i0 + cc];
    }
    __syncthreads();
    if (tid < 32) {
      double x = rhs[tid];
      double v = 0.0;
      for (int j = 0; j < 32; ++j) {
        double xj = __shfl(x, j, 64);
        double wj = xj * rdi[i0 + j];
        if (tid == j) v = wj;
        if (tid > j) x -= Ldd[tid][j] * wj;
      }
      w[i0 + tid] = v;
    }
    __syncthreads();
  }
  _Float16 h = (_Float16)(float)w[tid];
  WbT[(size_t)c * D_ + tid] = h;   // WbT[k=c][i=tid], coalesced (sig uses this)
  {
    const int g = tid >> 4, lrr = tid & 15;
    const int ks = c >> 5, lqq = (c >> 3) & 3, jj = c & 7;
    WbP[(size_t)(g * 8 + ks) * 512 + (size_t)(lqq * 16 + lrr) * 8 + jj] = h;
  }
}

// ---------------- kernel 5: signatures, normalized, packed MFMA-fragment layout -------
__global__ void sig_kernel(const float* __restrict__ S, const _Float16* __restrict__ WbT,
                           _Float16* __restrict__ sHatP) {
  int c = blockIdx.x, i = threadIdx.x;
  const int g = c >> 4, lr = c & 15;
  const int ks = i >> 5, lq = (i >> 3) & 3, jj = i & 7;
  const size_t off = (size_t)(g * 8 + ks) * 512 + (size_t)(lq * 16 + lr) * 8 + jj;
  if (c >= C_) { sHatP[off] = (_Float16)0.0f; return; }  // pad classes exactly 0
  __shared__ float srow[D_];
  __shared__ float wred[4];
  srow[i] = S[c * D_ + i];
  __syncthreads();
  float t = 0.f;
  for (int k = 0; k < D_; ++k) t += (float)WbT[k * D_ + i] * srow[k];
  float ss = t * t;
#pragma unroll
  for (int d = 1; d < 64; d <<= 1) ss += __shfl_xor(ss, d, 64);
  if ((i & 63) == 0) wred[i >> 6] = ss;
  __syncthreads();
  float tot = wred[0] + wred[1] + wred[2] + wred[3];
  float rn = 1.0f / fmaxf(sqrtf(tot), 1e-12f);
  sHatP[off] = (_Float16)(t * rn);
}

// ---------------- kernel 8: FUSED whiten + GEMM + logsumexp + finalize ----------------
// Half-chunk B staging (2x32KB, counted vmcnt(16)) frees 66.5KB LDS for a per-wave
// store-bounce: every outACE store is ONE contiguous 256B wave-instruction (was
// 4 fragmented 64B segments -> HBM write efficiency ~2x).
__global__ __launch_bounds__(1024) void ace_kernel(const float* __restrict__ X,
                                                   const float* __restrict__ means,
                                                   const _Float16* __restrict__ WbP,
                                                   const _Float16* __restrict__ sHatP,
                                                   const int* __restrict__ labels,
                                                   float* __restrict__ out,
                                                   double* __restrict__ acc_loss,
                                                   unsigned int* __restrict__ counter) {
  // layout: [0,65536) Bsh[2][16384] f16 | [65536, 65536+66560) xfer (16 waves x 1040 f32)
  // phases 1-2 reuse [0,131072) as Wsh / xs (barrier-separated).
  __shared__ __align__(16) char ldsraw[132096];
  __shared__ float msh[D_];
  __shared__ float part[64];
  _Float16* const Wsh = (_Float16*)ldsraw;
  char* const xsC = ldsraw;
  _Float16* const Bsh = (_Float16*)ldsraw;          // [2][16384]
  float* const xferAll = (float*)(ldsraw + 65536);  // 16 x 1040 floats (row pad +1)
  float* const outACE = out + 1;

  const int tid = threadIdx.x;
  const int wid = tid >> 6, l = tid & 63, lr = l & 15, lq = l >> 4;
  const int rowbase = blockIdx.x * 256;
  const int wrow = rowbase + wid * 16;           // this wave's 16-row strip
  const int arow = wrow + lr;                    // A-operand row (global)

  // ---- phase 1: stage WbP (128 KB) ----
  if (tid < 256) msh[tid] = means[tid];
#pragma unroll
  for (int s = 0; s < 8; ++s) {
    const int off = (wid * 8 + s) * 512;
    __builtin_amdgcn_global_load_lds(
        (const __attribute__((address_space(1))) unsigned int*)(WbP + off + l * 8),
        (__attribute__((address_space(3))) unsigned int*)(Wsh + off), 16, 0, 0);
  }
  __syncthreads();

  // ---- phase 2: whiten (X - m) @ W^T for this wave's 16 rows ----
  f16x8 af[8];
#pragma unroll
  for (int ks = 0; ks < 8; ++ks) {
    const float* xp = X + (size_t)arow * D_ + lq * 8 + ks * 32;
    const float4 x0 = *(const float4*)(xp);
    const float4 x1 = *(const float4*)(xp + 4);
    const int mb = lq * 8 + ks * 32;
    af[ks][0] = (_Float16)(x0.x - msh[mb + 0]);
    af[ks][1] = (_Float16)(x0.y - msh[mb + 1]);
    af[ks][2] = (_Float16)(x0.z - msh[mb + 2]);
    af[ks][3] = (_Float16)(x0.w - msh[mb + 3]);
    af[ks][4] = (_Float16)(x1.x - msh[mb + 4]);
    af[ks][5] = (_Float16)(x1.y - msh[mb + 5]);
    af[ks][6] = (_Float16)(x1.z - msh[mb + 6]);
    af[ks][7] = (_Float16)(x1.w - msh[mb + 7]);
  }
  f32x4 wacc[16];
#pragma unroll
  for (int u = 0; u < 16; ++u) wacc[u] = (f32x4){0.f, 0.f, 0.f, 0.f};
  {
    const _Float16* wb = Wsh + (size_t)l * 8;
#pragma unroll
    for (int ks = 0; ks < 8; ++ks) {
#pragma unroll
      for (int u = 0; u < 16; ++u) {
        f16x8 bf = *(const f16x8*)(wb + (u * 8 + ks) * 512);
        wacc[u] = __builtin_amdgcn_mfma_f32_16x16x32_f16(af[ks], bf, wacc[u], 0, 0, 0);
      }
    }
  }
  float ss[4] = {0.f, 0.f, 0.f, 0.f};
#pragma unroll
  for (int u = 0; u < 16; ++u)
#pragma unroll
    for (int j = 0; j < 4; ++j) ss[j] += wacc[u][j] * wacc[u][j];
#pragma unroll
  for (int d = 1; d < 16; d <<= 1) {
#pragma unroll
    for (int j = 0; j < 4; ++j) ss[j] += __shfl_xor(ss[j], d, 64);
  }
  float rx[4];
#pragma unroll
  for (int j = 0; j < 4; ++j) rx[j] = 1.0f / fmaxf(sqrtf(ss[j]), 1e-12f);

  __syncthreads();   // all waves done reading Wsh

  // ---- write whitened strip to LDS (swizzled), re-read as A-fragments ----
#pragma unroll
  for (int u = 0; u < 16; ++u) {
#pragma unroll
    for (int j = 0; j < 4; ++j) {
      const int rowl = wid * 16 + lq * 4 + j;
      const int byte = (rowl * 512 + (u * 16 + lr) * 2) ^ ((rowl & 7) << 4);
      *(_Float16*)(xsC + byte) = (_Float16)wacc[u][j];
    }
  }
  __syncthreads();   // writes visible
  f16x8 a[8];
  {
    const int rowA = wid * 16 + lr;
#pragma unroll
    for (int ks = 0; ks < 8; ++ks) {
      const int byte = (rowA * 512 + ks * 64 + lq * 16) ^ ((rowA & 7) << 4);
      a[ks] = *(const f16x8*)(xsC + byte);
    }
  }
  __syncthreads();   // all A-frag reads done before Bsh staging overwrites

  // ---- phase 3: GEMM over classes, 16 half-chunks (64 cols each), bounce stores ----
  int lab[4]; float ssum[4], num[4];
#pragma unroll
  for (int j = 0; j < 4; ++j) {
    lab[j] = labels[wrow + lq * 4 + j];
    ssum[j] = 0.f; num[j] = 0.f;
  }

#define STAGE(bufi, hci) do {                                                        \
    const _Float16* _src = sHatP + (size_t)(hci) * 16384;                            \
    _Float16* _dst = Bsh + (size_t)(bufi) * 16384;                                   \
    _Pragma("unroll")                                                                \
    for (int _s = 0; _s < 2; ++_s) {                                                 \
      const int _off = wid * 1024 + _s * 512;                                        \
      __builtin_amdgcn_global_load_lds(                                              \
          (const __attribute__((address_space(1))) unsigned int*)(_src + _off + l * 8), \
          (__attribute__((address_space(3))) unsigned int*)(_dst + _off), 16, 0, 0); \
    } } while (0)

  float* const xf = xferAll + wid * 1040;        // wave-private slab, 16 rows x 65 f32

  STAGE(0, 0);
  __syncthreads();                               // prologue: full drain once
  int buf = 0;
  for (int hc = 0; hc < 16; ++hc) {
    if (hc < 15) {
      STAGE(buf ^ 1, hc + 1);
      __builtin_amdgcn_sched_barrier(0);         // pin stage loads before compute/stores
    }
    const _Float16* bb = Bsh + (size_t)buf * 16384 + (size_t)l * 8;
    f32x4 acc[4];
#pragma unroll
    for (int t = 0; t < 4; ++t) acc[t] = (f32x4){0.f, 0.f, 0.f, 0.f};
#pragma unroll
    for (int ks = 0; ks < 8; ++ks) {
#pragma unroll
      for (int t = 0; t < 4; ++t) {
        f16x8 bf = *(const f16x8*)(bb + (t * 8 + ks) * 512);
        acc[t] = __builtin_amdgcn_mfma_f32_16x16x32_f16(a[ks], bf, acc[t], 0, 0, 0);
      }
    }
    // epilogue: softmax bookkeeping in registers + bounce write (wave-private LDS)
#pragma unroll
    for (int t = 0; t < 4; ++t) {
      const int col = hc * 64 + t * 16 + lr;
#pragma unroll
      for (int j = 0; j < 4; ++j) {
        float v = acc[t][j] * rx[j];
        ssum[j] += __expf(v - 1.0f);
        num[j] = (col == lab[j]) ? v : num[j];
        xf[(lq * 4 + j) * 65 + t * 16 + lr] = v;
      }
    }
    // bounce read + contiguous 256B row stores (wave-coherent; lgkm auto-waited)
    {
      const int colS = hc * 64 + l;
      if (colS < C_) {
#pragma unroll
        for (int r = 0; r < 16; ++r)
          outACE[(size_t)(wrow + r) * C_ + colS] = xf[r * 65 + l];
      }
    }
    if (hc < 15) {
      __builtin_amdgcn_sched_barrier(0);
      asm volatile("s_waitcnt vmcnt(16)" ::: "memory");  // retires the 2 stage loads
      __builtin_amdgcn_s_barrier();
      __builtin_amdgcn_sched_barrier(0);
    }
    buf ^= 1;
  }
#undef STAGE

#pragma unroll
  for (int d2 = 1; d2 < 16; d2 <<= 1) {
#pragma unroll
    for (int j = 0; j < 4; ++j) {
      ssum[j] += __shfl_xor(ssum[j], d2, 64);
      num[j]  += __shfl_xor(num[j], d2, 64);
    }
  }
  if (lr == 0) {
    const float padcorr = 24.0f * __expf(-1.0f);
    float contrib = 0.f;
#pragma unroll
    for (int j = 0; j < 4; ++j)
      contrib += num[j] - (1.0f + __logf(ssum[j] - padcorr));
    part[wid * 4 + lq] = contrib;
  }
  __syncthreads();
  if (tid == 0) {
    float s = 0.f;
#pragma unroll
    for (int p2 = 0; p2 < 64; ++p2) s += part[p2];
    atomicAdd(acc_loss, (double)s);
    __threadfence();
    unsigned int old = atomicAdd(counter, 1u);
    if (old == (unsigned int)(gridDim.x - 1)) {
      __threadfence();
      double tot = atomicAdd(acc_loss, 0.0);    // coherent read of final sum
      out[0] = (float)(-tot / (double)B_);
    }
  }
}

extern "C" void kernel_launch(void* const* d_in, const int* in_sizes, int n_in,
                              void* d_out, int out_size, void* d_ws, size_t ws_size,
                              hipStream_t stream) {
  const float* X      = (const float*)d_in[0];
  const int*   labels = (const int*)d_in[1];
  const float* S      = (const float*)d_in[2];
  const float* means  = (const float*)d_in[3];
  const float* bc     = (const float*)d_in[4];
  float* out = (float*)d_out;

  char* w = (char*)d_ws;
  double*       acc   = (double*)(w + 0);
  unsigned int* cnt   = (unsigned int*)(w + 128);
  double*       C64   = (double*)(w + 256);       // 512 KB
  _Float16*     WbP   = (_Float16*)(w + 524544);  // 128 KB packed B (whiten)
  _Float16*     WbT   = (_Float16*)(w + 655616);  // 128 KB (sig)
  _Float16*     sHatP = (_Float16*)(w + 786688);  // 512 KB packed (1024 classes)

  cov_kernel<<<64, 256, 0, stream>>>(bc, C64, acc, cnt);
  for (int p = 0; p < 4; ++p) {
    chol_panel<<<1, 256, 0, stream>>>(C64, p);
    int nt = 3 - p;
    if (nt > 0) chol_trail<<<nt * (nt + 1) / 2, 256, 0, stream>>>(C64, p);
  }
  inv_kernel<<<256, 256, 0, stream>>>(C64, WbP, WbT);
  sig_kernel<<<1024, 256, 0, stream>>>(S, WbT, sHatP);
  ace_kernel<<<256, 1024, 0, stream>>>(X, means, WbP, sHatP, labels, out, acc, cnt);
}